// Round 2
// baseline (812.314 us; speedup 1.0000x reference)
//
#include <hip/hip_runtime.h>
#include <hip/hip_bf16.h>
#include <math.h>

#define BATCH 32
#define DFEAT 21
#define NPTS 1024
#define KSEL 32
#define NOUT 64

typedef unsigned long long u64;

__device__ __forceinline__ unsigned ord32(float f) {
    unsigned u = __float_as_uint(f);
    return ((int)u >= 0) ? (u | 0x80000000u) : ~u;
}
__device__ __forceinline__ float iord32(unsigned u) {
    unsigned s = (u & 0x80000000u) ? (u & 0x7FFFFFFFu) : ~u;
    return __uint_as_float(s);
}
__device__ __forceinline__ u64 mkkey(unsigned o, int m) {
    return ((u64)o << 32) | (unsigned)(~m);
}

// Dual-row bitonic sort, descending by u64 key. Element e = lane + 64*i.
// After sort, rank-r element lives at reg r/64... for R<=2: reg 0 lanes 0..63
// hold ranks 0..63 (we only consume ranks 0..31).
template <int R>
__device__ __forceinline__ void sort2_desc(u64* A, u64* B, int lane) {
    const int NEL = R * 64;
    #pragma unroll
    for (int k = 2; k <= NEL; k <<= 1) {
        #pragma unroll
        for (int j = k >> 1; j >= 1; j >>= 1) {
            if (j >= 64) {
                const int rj = j >> 6;
                #pragma unroll
                for (int i = 0; i < R; ++i) {
                    if ((i & rj) == 0) {
                        const int e = lane + 64 * i;
                        const bool wm = ((e & k) == 0);
                        u64 x = A[i], y = A[i ^ rj];
                        u64 mx = x > y ? x : y, mn = x > y ? y : x;
                        A[i] = wm ? mx : mn; A[i ^ rj] = wm ? mn : mx;
                        x = B[i]; y = B[i ^ rj];
                        mx = x > y ? x : y; mn = x > y ? y : x;
                        B[i] = wm ? mx : mn; B[i ^ rj] = wm ? mn : mx;
                    }
                }
            } else {
                #pragma unroll
                for (int i = 0; i < R; ++i) {
                    const int e = lane + 64 * i;
                    const bool wm = ((e & j) == 0) == ((e & k) == 0);
                    const u64 oa = __shfl_xor(A[i], j);
                    const u64 ob = __shfl_xor(B[i], j);
                    const u64 mxa = A[i] > oa ? A[i] : oa;
                    const u64 mna = A[i] > oa ? oa : A[i];
                    A[i] = wm ? mxa : mna;
                    const u64 mxb = B[i] > ob ? B[i] : ob;
                    const u64 mnb = B[i] > ob ? ob : B[i];
                    B[i] = wm ? mxb : mnb;
                }
            }
        }
    }
}

// Exact rare-path: extract top-32 in order with no stored state (keys distinct,
// strictly decreasing winners). Returns rank-lane winner for lane<32.
__device__ __noinline__ u64 knn_fallback(const unsigned* ord, int lane) {
    u64 W = ~0ULL, win = 0ULL;
    for (int it = 0; it < 32; ++it) {
        u64 best = 0ULL;
        #pragma unroll
        for (int i = 0; i < 16; ++i) {
            const u64 k = mkkey(ord[i], i * 64 + lane);
            if (k < W && k > best) best = k;
        }
        #pragma unroll
        for (int off = 32; off >= 1; off >>= 1) {
            const u64 o = __shfl_xor(best, off);
            best = o > best ? o : best;
        }
        win = (lane == it) ? best : win;
        W = best;
    }
    return win;
}

// ---------------------------------------------------------------------------
// Kernel 1: per-row KNN. 2 rows per wave concurrently; threshold prefilter
// (32nd-largest of lane maxima) -> candidate buffer -> adaptive bitonic sort.
// grid 256 (32 b x 8 chunks), block 1024 (16 waves x 8 rows), dyn LDS 120KB.
// ---------------------------------------------------------------------------
__global__ __launch_bounds__(1024, 4) void knn_kernel(
        const float* __restrict__ x,
        int* __restrict__ idx_ws, float* __restrict__ dist_ws,
        float* __restrict__ sub_ws) {
    extern __shared__ float smem[];
    float* xs  = smem;                       // [21][1024]
    float* xxs = smem + DFEAT * NPTS;        // [1024]
    u64* cand  = (u64*)(smem + DFEAT * NPTS + NPTS);  // [16][2][128]

    const int tid  = threadIdx.x;
    const int lane = tid & 63;
    const int w    = tid >> 6;
    const int b      = blockIdx.x >> 3;
    const int nchunk = blockIdx.x & 7;

    const float* xb = x + (size_t)b * DFEAT * NPTS;
    for (int i = tid; i < DFEAT * NPTS; i += 1024) xs[i] = xb[i];
    __syncthreads();
    {
        const int m = tid;
        float s = 0.f;
        #pragma unroll
        for (int d = 0; d < DFEAT; ++d) { float v = xs[d * NPTS + m]; s = fmaf(v, v, s); }
        xxs[m] = s;
    }
    __syncthreads();

    u64* cwA = cand + (w * 2 + 0) * 128;
    u64* cwB = cand + (w * 2 + 1) * 128;

    float xxm[16];
    #pragma unroll
    for (int i = 0; i < 16; ++i) xxm[i] = xxs[i * 64 + lane];

    const int nbase = nchunk * 128 + w * 8;

    for (int rp = 0; rp < 4; ++rp) {
        const int na = nbase + rp * 2;
        const int nb = na + 1;

        // ---- distances for both rows (shared xs reads) ----
        float accA[16], accB[16];
        #pragma unroll
        for (int i = 0; i < 16; ++i) { accA[i] = 0.f; accB[i] = 0.f; }
        #pragma unroll
        for (int d = 0; d < DFEAT; ++d) {
            const float* rowp = xs + d * NPTS;
            const float xda = rowp[na];
            const float xdb = rowp[nb];
            #pragma unroll
            for (int i = 0; i < 16; ++i) {
                const float t = rowp[i * 64 + lane];
                accA[i] = fmaf(t, xda, accA[i]);
                accB[i] = fmaf(t, xdb, accB[i]);
            }
        }
        const float xxna = xxs[na], xxnb = xxs[nb];
        unsigned ordA[16], ordB[16];
        #pragma unroll
        for (int i = 0; i < 16; ++i) {
            ordA[i] = ord32((2.f * accA[i] - xxna) - xxm[i]);
            ordB[i] = ord32((2.f * accB[i] - xxnb) - xxm[i]);
        }

        // ---- per-lane max (tie -> smallest m, via ascending-i strict >) ----
        unsigned boA = ordA[0], boB = ordB[0];
        int bmA = lane, bmB = lane;
        #pragma unroll
        for (int i = 1; i < 16; ++i) {
            if (ordA[i] > boA) { boA = ordA[i]; bmA = i * 64 + lane; }
            if (ordB[i] > boB) { boB = ordB[i]; bmB = i * 64 + lane; }
        }
        u64 va = mkkey(boA, bmA), vb = mkkey(boB, bmB);

        // ---- threshold = 32nd largest of the 64 lane maxima (asc bitonic) --
        #pragma unroll
        for (int kk = 2; kk <= 64; kk <<= 1) {
            #pragma unroll
            for (int j = kk >> 1; j >= 1; j >>= 1) {
                const u64 oa = __shfl_xor(va, j);
                const u64 ob = __shfl_xor(vb, j);
                const bool up      = ((lane & kk) == 0);
                const bool upper   = ((lane & j) != 0);
                const bool takeMax = (upper == up);
                va = (takeMax ? (oa > va) : (oa < va)) ? oa : va;
                vb = (takeMax ? (ob > vb) : (ob < vb)) ? ob : vb;
            }
        }
        const u64 Ta = __shfl(va, 32);
        const u64 Tb = __shfl(vb, 32);

        // ---- count + exclusive prefix for compaction ----
        int ca = 0, cb = 0;
        #pragma unroll
        for (int i = 0; i < 16; ++i) {
            ca += (mkkey(ordA[i], i * 64 + lane) >= Ta) ? 1 : 0;
            cb += (mkkey(ordB[i], i * 64 + lane) >= Tb) ? 1 : 0;
        }
        int sa = ca, sb = cb;
        #pragma unroll
        for (int off = 1; off < 64; off <<= 1) {
            const int t2a = __shfl_up(sa, off);
            const int t2b = __shfl_up(sb, off);
            if (lane >= off) { sa += t2a; sb += t2b; }
        }
        const int baseA = sa - ca, baseB = sb - cb;
        const int CtA = __shfl(sa, 63), CtB = __shfl(sb, 63);

        // ---- compact candidates to LDS ----
        {
            int p = baseA;
            #pragma unroll
            for (int i = 0; i < 16; ++i) {
                const u64 k = mkkey(ordA[i], i * 64 + lane);
                if (k >= Ta) { if (p < 128) cwA[p] = k; ++p; }
            }
            p = baseB;
            #pragma unroll
            for (int i = 0; i < 16; ++i) {
                const u64 k = mkkey(ordB[i], i * 64 + lane);
                if (k >= Tb) { if (p < 128) cwB[p] = k; ++p; }
            }
        }
        __asm__ volatile("s_waitcnt lgkmcnt(0)" ::: "memory");

        // ---- adaptive bitonic top-32 (exact order) ----
        u64 keyA, keyB;
        if (CtA <= 128 && CtB <= 128) {
            if (CtA <= 64 && CtB <= 64) {
                u64 a0 = (lane < CtA) ? cwA[lane] : 0ULL;
                u64 b0 = (lane < CtB) ? cwB[lane] : 0ULL;
                sort2_desc<1>(&a0, &b0, lane);
                keyA = a0; keyB = b0;
            } else {
                u64 a[2], bb[2];
                #pragma unroll
                for (int i = 0; i < 2; ++i) {
                    const int ci = lane + 64 * i;
                    a[i]  = (ci < CtA) ? cwA[ci] : 0ULL;
                    bb[i] = (ci < CtB) ? cwB[ci] : 0ULL;
                }
                sort2_desc<2>(a, bb, lane);
                keyA = a[0]; keyB = bb[0];
            }
        } else {
            keyA = knn_fallback(ordA, lane);
            keyB = knn_fallback(ordB, lane);
        }

        // ---- epilogue: lane r (<32) holds rank-r neighbor ----
        const int   mA = (int)(~(unsigned)keyA);
        const int   mB = (int)(~(unsigned)keyB);
        const float pdA = iord32((unsigned)(keyA >> 32));
        const float pdB = iord32((unsigned)(keyB >> 32));
        const int m0A = __shfl(mA, 0);
        const int m0B = __shfl(mB, 0);
        if (lane < KSEL) {
            const size_t oA = ((size_t)(b * NPTS + na)) * KSEL + lane;
            const size_t oB = ((size_t)(b * NPTS + nb)) * KSEL + lane;
            idx_ws[oA]  = mA;          idx_ws[oB]  = mB;
            dist_ws[oA] = -pdA;        dist_ws[oB] = -pdB;
            float svA = 0.f, svB = 0.f;
            #pragma unroll
            for (int d = 0; d < DFEAT; ++d) {
                svA = fmaf(xs[d * NPTS + mA], xs[d * NPTS + m0A], svA);
                svB = fmaf(xs[d * NPTS + mB], xs[d * NPTS + m0B], svB);
            }
            sub_ws[oA] = svA;          sub_ws[oB] = svB;
        }
    }
}

// ---------------------------------------------------------------------------
// Kernel 2a: partial Gram of q = sub^2 over 256-row chunks.
// norm2[b,k,j] = sum_n q[n,k] q[n,j]. grid 128 (b x 4), block 1024.
// ---------------------------------------------------------------------------
__global__ __launch_bounds__(1024) void norm_part_kernel(
        const float* __restrict__ sub_ws, float* __restrict__ npart) {
    __shared__ float qS[256 * 33];
    const int tid = threadIdx.x;
    const int b = blockIdx.x >> 2;
    const int c = blockIdx.x & 3;
    const float* sb = sub_ws + ((size_t)b * NPTS + c * 256) * KSEL;
    for (int i = tid; i < 256 * 32; i += 1024) {
        const float v = sb[i];
        qS[(i >> 5) * 33 + (i & 31)] = v * v;
    }
    __syncthreads();
    const int k = tid >> 5, j = tid & 31;
    float acc = 0.f;
    #pragma unroll 4
    for (int n = 0; n < 256; ++n)
        acc = fmaf(qS[n * 33 + k], qS[n * 33 + j], acc);
    npart[(size_t)blockIdx.x * 1024 + tid] = acc;
}

// ---------------------------------------------------------------------------
// Kernel 2b: combine partials -> recip = 1/max(sqrt(norm2),1e-12). grid 32.
// ---------------------------------------------------------------------------
__global__ __launch_bounds__(1024) void norm_combine_kernel(
        const float* __restrict__ npart, float* __restrict__ recip_ws) {
    const int b = blockIdx.x, t = threadIdx.x;
    const float s = npart[((size_t)b * 4 + 0) * 1024 + t]
                  + npart[((size_t)b * 4 + 1) * 1024 + t]
                  + npart[((size_t)b * 4 + 2) * 1024 + t]
                  + npart[((size_t)b * 4 + 3) * 1024 + t];
    recip_ws[(size_t)b * NPTS + t] = 1.0f / fmaxf(sqrtf(s), 1e-12f);
}

// ---------------------------------------------------------------------------
// Kernel 3: gm_red + BN1/BN2 f64 partial sums. grid 4096, block 256.
// ---------------------------------------------------------------------------
__global__ __launch_bounds__(256) void gmred_kernel(
        const float* __restrict__ sub_ws, const float* __restrict__ dist_ws,
        const float* __restrict__ recip_ws, const float* __restrict__ w_gm,
        float* __restrict__ gmred_ws, double* __restrict__ part12) {
    __shared__ float recipS[32 * 33];
    __shared__ float subS[8 * 32];
    __shared__ float subWS[8 * 32];
    __shared__ double redS[4][4];

    const int tid = threadIdx.x;
    const int b   = blockIdx.x >> 7;
    const int n0  = (blockIdx.x & 127) * 8;

    for (int i = tid; i < 1024; i += 256)
        recipS[(i >> 5) * 33 + (i & 31)] = recip_ws[(size_t)b * NPTS + i];
    {
        const float sv = sub_ws[((size_t)(b * NPTS + n0)) * KSEL + tid];
        subS[tid]  = sv;
        subWS[tid] = sv * w_gm[tid & 31];
    }
    __syncthreads();

    const int r = tid >> 5, k = tid & 31;
    float s = 0.f;
    #pragma unroll
    for (int c = 0; c < 32; ++c)
        s = fmaf(subWS[r * 32 + c], recipS[k * 33 + c], s);
    const float g = subS[r * 32 + k] * s;
    const size_t row = (size_t)(b * NPTS + n0 + r);
    gmred_ws[row * KSEL + k] = g;
    const float dv = dist_ws[row * KSEL + k];

    double s1 = (double)dv, s2 = (double)dv * (double)dv;
    double s3 = (double)g,  s4 = (double)g * (double)g;
    #pragma unroll
    for (int off = 32; off >= 1; off >>= 1) {
        s1 += __shfl_xor(s1, off);
        s2 += __shfl_xor(s2, off);
        s3 += __shfl_xor(s3, off);
        s4 += __shfl_xor(s4, off);
    }
    if ((tid & 63) == 0) {
        const int wv = tid >> 6;
        redS[wv][0] = s1; redS[wv][1] = s2; redS[wv][2] = s3; redS[wv][3] = s4;
    }
    __syncthreads();
    if (tid == 0) {
        double a0 = 0, a1 = 0, a2 = 0, a3 = 0;
        #pragma unroll
        for (int wv = 0; wv < 4; ++wv) {
            a0 += redS[wv][0]; a1 += redS[wv][1]; a2 += redS[wv][2]; a3 += redS[wv][3];
        }
        part12[(size_t)blockIdx.x * 4 + 0] = a0;
        part12[(size_t)blockIdx.x * 4 + 1] = a1;
        part12[(size_t)blockIdx.x * 4 + 2] = a2;
        part12[(size_t)blockIdx.x * 4 + 3] = a3;
    }
}

// ---------------------------------------------------------------------------
// Kernel 4: uc[b,n,o] = sum_d w_up[o,d] * x[b,d,n]. grid 2048, block 256.
// ---------------------------------------------------------------------------
__global__ __launch_bounds__(256) void uc_kernel(
        const float* __restrict__ x, const float* __restrict__ w_up,
        float* __restrict__ uc_ws) {
    __shared__ float wS[NOUT * DFEAT];
    __shared__ float xS[DFEAT * 16];
    const int tid = threadIdx.x;
    const int b  = blockIdx.x >> 6;
    const int n0 = (blockIdx.x & 63) * 16;
    for (int i = tid; i < NOUT * DFEAT; i += 256) wS[i] = w_up[i];
    for (int i = tid; i < DFEAT * 16; i += 256) {
        const int d = i >> 4, c = i & 15;
        xS[i] = x[((size_t)b * DFEAT + d) * NPTS + n0 + c];
    }
    __syncthreads();
    const int o = tid & 63, g = tid >> 6;
    #pragma unroll
    for (int nn = g; nn < 16; nn += 4) {
        float a = 0.f;
        #pragma unroll
        for (int d = 0; d < DFEAT; ++d)
            a = fmaf(wS[o * DFEAT + d], xS[d * 16 + nn], a);
        uc_ws[((size_t)(b * NPTS) + n0 + nn) * NOUT + o] = a;
    }
}

// ---------------------------------------------------------------------------
// Kernel 5: reduce BN1/BN2 partials -> folded scale/offset consts
// ---------------------------------------------------------------------------
__global__ __launch_bounds__(256) void reduce12_kernel(
        const double* __restrict__ part12, int nblocks,
        const float* __restrict__ w_dist,
        const float* __restrict__ g1, const float* __restrict__ b1,
        const float* __restrict__ g2, const float* __restrict__ b2,
        float* __restrict__ consts) {
    __shared__ double S[256][4];
    const int t = threadIdx.x;
    double a0 = 0, a1 = 0, a2 = 0, a3 = 0;
    for (int i = t; i < nblocks; i += 256) {
        a0 += part12[(size_t)i * 4 + 0];
        a1 += part12[(size_t)i * 4 + 1];
        a2 += part12[(size_t)i * 4 + 2];
        a3 += part12[(size_t)i * 4 + 3];
    }
    S[t][0] = a0; S[t][1] = a1; S[t][2] = a2; S[t][3] = a3;
    __syncthreads();
    for (int off = 128; off >= 1; off >>= 1) {
        if (t < off) {
            S[t][0] += S[t + off][0]; S[t][1] += S[t + off][1];
            S[t][2] += S[t + off][2]; S[t][3] += S[t + off][3];
        }
        __syncthreads();
    }
    if (t == 0) {
        const double M = (double)BATCH * NPTS * KSEL;
        const double E1 = S[0][0] / M, E2 = S[0][1] / M;
        const double wd = (double)w_dist[0];
        const double mean1 = wd * E1;
        const double var1  = wd * wd * (E2 - E1 * E1);
        const double istd1 = 1.0 / sqrt(var1 + 1e-5);
        consts[0] = (float)(wd * istd1 * (double)g1[0]);
        consts[1] = (float)((double)b1[0] - mean1 * istd1 * (double)g1[0]);
        const double F1 = S[0][2] / M, F2 = S[0][3] / M;
        const double var2  = F2 - F1 * F1;
        const double istd2 = 1.0 / sqrt(var2 + 1e-5);
        consts[2] = (float)(istd2 * (double)g2[0]);
        consts[3] = (float)((double)b2[0] - F1 * istd2 * (double)g2[0]);
    }
}

// ---------------------------------------------------------------------------
// Kernel 6: gate + BN3 partial stats. grid 512, block 256.
// ---------------------------------------------------------------------------
__global__ __launch_bounds__(256) void gate_stats_kernel(
        const float* __restrict__ dist_ws, const float* __restrict__ gmred_ws,
        const int* __restrict__ idx_ws, const float* __restrict__ uc_ws,
        const float* __restrict__ consts,
        float* __restrict__ gate_ws, double* __restrict__ part3) {
    const int tid = threadIdx.x, lane = tid & 63, w = tid >> 6;
    const int row0 = blockIdx.x * 64;
    const float A1 = consts[0], C1 = consts[1], A2 = consts[2], C2 = consts[3];
    double sum = 0.0, ssq = 0.0;
    for (int rr = 0; rr < 16; ++rr) {
        const int row = row0 + w * 16 + rr;
        const int b = row >> 10;
        float gate = 0.f; int jj = 0;
        if (lane < KSEL) {
            const size_t rbase = (size_t)row * KSEL + lane;
            const float dv = dist_ws[rbase];
            const float gv = gmred_ws[rbase];
            jj = idx_ws[rbase];
            const float z1 = fmaf(dv, A1, C1);
            const float z2 = fmaf(gv, A2, C2);
            const float w1 = 1.f / (1.f + __expf(-z1));
            const float w2 = 1.f / (1.f + __expf(-z2));
            gate = w1 * w2;
            gate_ws[rbase] = gate;
        }
        const float ucr = uc_ws[(size_t)row * NOUT + lane];
        const float* ucb = uc_ws + ((size_t)(b * NPTS)) * NOUT;
        #pragma unroll 8
        for (int k = 0; k < KSEL; ++k) {
            const float gk = __shfl(gate, k);
            const int   jk = __shfl(jj, k);
            const float ucn = ucb[(size_t)jk * NOUT + lane];
            const float up  = fmaf(gk, ucn - ucr, ucr);
            sum += (double)up;
            ssq = fma((double)up, (double)up, ssq);
        }
    }
    __shared__ double p3[4][64][2];
    p3[w][lane][0] = sum; p3[w][lane][1] = ssq;
    __syncthreads();
    if (w == 0) {
        const double s = p3[0][lane][0] + p3[1][lane][0] + p3[2][lane][0] + p3[3][lane][0];
        const double q = p3[0][lane][1] + p3[1][lane][1] + p3[2][lane][1] + p3[3][lane][1];
        part3[((size_t)blockIdx.x * 64 + lane) * 2 + 0] = s;
        part3[((size_t)blockIdx.x * 64 + lane) * 2 + 1] = q;
    }
}

// ---------------------------------------------------------------------------
// Kernel 7: reduce BN3 partials -> per-channel A/C
// ---------------------------------------------------------------------------
__global__ __launch_bounds__(256) void reduce3_kernel(
        const double* __restrict__ part3,
        const float* __restrict__ g3, const float* __restrict__ b3,
        float* __restrict__ consts3) {
    const int t = threadIdx.x;
    const int o = t & 63, gq = t >> 6;
    double s = 0, q = 0;
    for (int i = gq; i < 512; i += 4) {
        s += part3[((size_t)i * 64 + o) * 2 + 0];
        q += part3[((size_t)i * 64 + o) * 2 + 1];
    }
    __shared__ double S[4][64][2];
    S[gq][o][0] = s; S[gq][o][1] = q;
    __syncthreads();
    if (t < 64) {
        const double ss = S[0][o][0] + S[1][o][0] + S[2][o][0] + S[3][o][0];
        const double qq = S[0][o][1] + S[1][o][1] + S[2][o][1] + S[3][o][1];
        const double M = (double)BATCH * NPTS * KSEL;
        const double mean = ss / M;
        const double var  = qq / M - mean * mean;
        const double istd = 1.0 / sqrt(var + 1e-5);
        consts3[o]      = (float)(istd * (double)g3[o]);
        consts3[64 + o] = (float)((double)b3[o] - mean * istd * (double)g3[o]);
    }
}

// ---------------------------------------------------------------------------
// Kernel 8: out[b,o,n] = mean_k lrelu(up*A[o]+C[o])
// ---------------------------------------------------------------------------
__global__ __launch_bounds__(256) void final_kernel(
        const float* __restrict__ gate_ws, const int* __restrict__ idx_ws,
        const float* __restrict__ uc_ws, const float* __restrict__ consts3,
        float* __restrict__ out) {
    const int tid = threadIdx.x, lane = tid & 63, w = tid >> 6;
    const int row0 = blockIdx.x * 64;
    const float A = consts3[lane], C = consts3[64 + lane];
    for (int rr = 0; rr < 16; ++rr) {
        const int row = row0 + w * 16 + rr;
        const int b = row >> 10, n = row & 1023;
        float gate = 0.f; int jj = 0;
        if (lane < KSEL) {
            gate = gate_ws[(size_t)row * KSEL + lane];
            jj   = idx_ws[(size_t)row * KSEL + lane];
        }
        const float ucr = uc_ws[(size_t)row * NOUT + lane];
        const float* ucb = uc_ws + ((size_t)(b * NPTS)) * NOUT;
        float acc = 0.f;
        #pragma unroll 8
        for (int k = 0; k < KSEL; ++k) {
            const float gk = __shfl(gate, k);
            const int   jk = __shfl(jj, k);
            const float ucn = ucb[(size_t)jk * NOUT + lane];
            const float up  = fmaf(gk, ucn - ucr, ucr);
            float z = fmaf(up, A, C);
            z = (z >= 0.f) ? z : 0.02f * z;
            acc += z;
        }
        out[((size_t)b * NOUT + lane) * NPTS + n] = acc * (1.f / 32.f);
    }
}

// ---------------------------------------------------------------------------
extern "C" void kernel_launch(void* const* d_in, const int* in_sizes, int n_in,
                              void* d_out, int out_size, void* d_ws, size_t ws_size,
                              hipStream_t stream) {
    const float* x      = (const float*)d_in[0];
    const float* w_dist = (const float*)d_in[2];
    const float* g1     = (const float*)d_in[3];
    const float* b1     = (const float*)d_in[4];
    const float* w_gm   = (const float*)d_in[5];
    const float* g2     = (const float*)d_in[6];
    const float* b2     = (const float*)d_in[7];
    const float* w_up   = (const float*)d_in[8];
    const float* g3     = (const float*)d_in[9];
    const float* b3     = (const float*)d_in[10];
    float* out = (float*)d_out;

    char* ws = (char*)d_ws;
    int*    idx_ws   = (int*)(ws + 0);
    float*  dist_ws  = (float*)(ws + ((size_t)4 << 20));
    float*  sub_ws   = (float*)(ws + ((size_t)8 << 20));
    float*  gmred_ws = (float*)(ws + ((size_t)12 << 20));
    float*  gate_ws  = (float*)(ws + ((size_t)16 << 20));
    float*  uc_ws    = (float*)(ws + ((size_t)20 << 20));
    float*  recip_ws = (float*)(ws + ((size_t)28 << 20));
    double* part12   = (double*)(ws + ((size_t)28 << 20) + 0x20000);
    double* part3    = (double*)(ws + ((size_t)28 << 20) + 0x40000);
    float*  consts   = (float*)(ws + ((size_t)28 << 20) + 0xC0000);
    float*  consts3  = consts + 4;
    // npart reuses the gmred region (fully consumed by norm_combine before
    // gmred_kernel writes it) -- 128*1024*4 = 512KB <= 4MB.
    float*  npart    = gmred_ws;

    knn_kernel<<<dim3(256), dim3(1024), 120 * 1024, stream>>>(x, idx_ws, dist_ws, sub_ws);
    norm_part_kernel<<<dim3(128), dim3(1024), 0, stream>>>(sub_ws, npart);
    norm_combine_kernel<<<dim3(32), dim3(1024), 0, stream>>>(npart, recip_ws);
    gmred_kernel<<<dim3(4096), dim3(256), 0, stream>>>(sub_ws, dist_ws, recip_ws, w_gm,
                                                       gmred_ws, part12);
    uc_kernel<<<dim3(2048), dim3(256), 0, stream>>>(x, w_up, uc_ws);
    reduce12_kernel<<<dim3(1), dim3(256), 0, stream>>>(part12, 4096, w_dist, g1, b1, g2, b2,
                                                       consts);
    gate_stats_kernel<<<dim3(512), dim3(256), 0, stream>>>(dist_ws, gmred_ws, idx_ws, uc_ws,
                                                           consts, gate_ws, part3);
    reduce3_kernel<<<dim3(1), dim3(256), 0, stream>>>(part3, g3, b3, consts3);
    final_kernel<<<dim3(512), dim3(256), 0, stream>>>(gate_ws, idx_ws, uc_ws, consts3, out);
}

// Round 3
// 253.784 us; speedup vs baseline: 3.2008x; 3.2008x over previous
//
#include <hip/hip_runtime.h>
#include <hip/hip_bf16.h>
#include <math.h>

#define BATCH 32
#define DFEAT 21
#define NPTS 1024
#define KSEL 32
#define NOUT 64

typedef unsigned long long u64;

__device__ __forceinline__ unsigned ord32(float f) {
    unsigned u = __float_as_uint(f);
    return ((int)u >= 0) ? (u | 0x80000000u) : ~u;
}
__device__ __forceinline__ float iord32(unsigned u) {
    unsigned s = (u & 0x80000000u) ? (u & 0x7FFFFFFFu) : ~u;
    return __uint_as_float(s);
}
__device__ __forceinline__ u64 mkkey(unsigned o, int m) {
    return ((u64)o << 32) | (unsigned)(~m);
}

// Bitonic sort, descending by u64 key. Element e = lane + 64*i.
// After sort, reg 0 lane r holds rank-r element (r = 0..63).
template <int R>
__device__ __forceinline__ void sort1_desc(u64* A, int lane) {
    const int NEL = R * 64;
    #pragma unroll
    for (int k = 2; k <= NEL; k <<= 1) {
        #pragma unroll
        for (int j = k >> 1; j >= 1; j >>= 1) {
            if (j >= 64) {
                const int rj = j >> 6;
                #pragma unroll
                for (int i = 0; i < R; ++i) {
                    if ((i & rj) == 0) {
                        const int e = lane + 64 * i;
                        const bool wm = ((e & k) == 0);
                        u64 x = A[i], y = A[i ^ rj];
                        const u64 mx = x > y ? x : y, mn = x > y ? y : x;
                        A[i] = wm ? mx : mn; A[i ^ rj] = wm ? mn : mx;
                    }
                }
            } else {
                #pragma unroll
                for (int i = 0; i < R; ++i) {
                    const int e = lane + 64 * i;
                    const bool wm = ((e & j) == 0) == ((e & k) == 0);
                    const u64 oa = __shfl_xor(A[i], j);
                    const u64 mxa = A[i] > oa ? A[i] : oa;
                    const u64 mna = A[i] > oa ? oa : A[i];
                    A[i] = wm ? mxa : mna;
                }
            }
        }
    }
}

// Exact rare-path: extract top-32 in order, no stored state (keys distinct).
// ord layout: ord[c*4+j] corresponds to m = c*256 + lane*4 + j.
__device__ __noinline__ u64 knn_fallback(const unsigned* ord, int lane) {
    u64 W = ~0ULL, win = 0ULL;
    for (int it = 0; it < 32; ++it) {
        u64 best = 0ULL;
        #pragma unroll
        for (int i = 0; i < 16; ++i) {
            const int m = (i >> 2) * 256 + lane * 4 + (i & 3);
            const u64 k = mkkey(ord[i], m);
            if (k < W && k > best) best = k;
        }
        #pragma unroll
        for (int off = 32; off >= 1; off >>= 1) {
            const u64 o = __shfl_xor(best, off);
            best = o > best ? o : best;
        }
        win = (lane == it) ? best : win;
        W = best;
    }
    return win;
}

// ---------------------------------------------------------------------------
// Kernel 1: per-row KNN. Single row per wave iteration (fits 64-VGPR budget,
// no spills); float4 LDS reads on the m side; threshold prefilter (32nd
// largest of 64 lane maxima) -> compaction -> adaptive bitonic sort.
// grid 256 (32 b x 8 chunks), block 1024 (16 waves x 8 rows), dyn LDS 104KB.
// ---------------------------------------------------------------------------
__global__ __launch_bounds__(1024) void knn_kernel(
        const float* __restrict__ x,
        int* __restrict__ idx_ws, float* __restrict__ dist_ws,
        float* __restrict__ sub_ws) {
    extern __shared__ float smem[];
    float* xs  = smem;                       // [21][1024]
    float* xxs = smem + DFEAT * NPTS;        // [1024]
    u64* cand  = (u64*)(smem + DFEAT * NPTS + NPTS);  // [16][128]

    const int tid  = threadIdx.x;
    const int lane = tid & 63;
    const int w    = tid >> 6;
    const int b      = blockIdx.x >> 3;
    const int nchunk = blockIdx.x & 7;

    const float* xb = x + (size_t)b * DFEAT * NPTS;
    for (int i = tid; i < DFEAT * NPTS; i += 1024) xs[i] = xb[i];
    __syncthreads();
    {
        const int m = tid;
        float s = 0.f;
        #pragma unroll
        for (int d = 0; d < DFEAT; ++d) { float v = xs[d * NPTS + m]; s = fmaf(v, v, s); }
        xxs[m] = s;
    }
    __syncthreads();

    u64* cw = cand + w * 128;
    const float4* xs4  = (const float4*)xs;
    const float4* xxs4 = (const float4*)xxs;

    // persistent: xx for this lane's 16 m values (m = c*256 + lane*4 + j)
    float4 xx4[4];
    #pragma unroll
    for (int c = 0; c < 4; ++c) xx4[c] = xxs4[c * 64 + lane];

    for (int r = 0; r < 8; ++r) {
        const int n = nchunk * 128 + w * 8 + r;

        // ---- distances: acc[c] = <x_n, x_m> for m = c*256+lane*4+{0..3} ----
        float4 acc[4];
        #pragma unroll
        for (int c = 0; c < 4; ++c) acc[c] = make_float4(0.f, 0.f, 0.f, 0.f);
        for (int d = 0; d < DFEAT; ++d) {
            const float xnd = xs[d * NPTS + n];
            #pragma unroll
            for (int c = 0; c < 4; ++c) {
                const float4 t = xs4[d * 256 + c * 64 + lane];
                acc[c].x = fmaf(t.x, xnd, acc[c].x);
                acc[c].y = fmaf(t.y, xnd, acc[c].y);
                acc[c].z = fmaf(t.z, xnd, acc[c].z);
                acc[c].w = fmaf(t.w, xnd, acc[c].w);
            }
        }
        const float xxn = xxs[n];
        unsigned ord[16];
        #pragma unroll
        for (int c = 0; c < 4; ++c) {
            ord[c * 4 + 0] = ord32((2.f * acc[c].x - xxn) - xx4[c].x);
            ord[c * 4 + 1] = ord32((2.f * acc[c].y - xxn) - xx4[c].y);
            ord[c * 4 + 2] = ord32((2.f * acc[c].z - xxn) - xx4[c].z);
            ord[c * 4 + 3] = ord32((2.f * acc[c].w - xxn) - xx4[c].w);
        }

        // ---- per-lane max key (key compare handles tie -> smallest m) ----
        u64 va = mkkey(ord[0], lane * 4);
        #pragma unroll
        for (int i = 1; i < 16; ++i) {
            const int m = (i >> 2) * 256 + lane * 4 + (i & 3);
            const u64 k = mkkey(ord[i], m);
            va = k > va ? k : va;
        }

        // ---- threshold = 32nd largest of 64 lane maxima (asc bitonic) ----
        #pragma unroll
        for (int kk = 2; kk <= 64; kk <<= 1) {
            #pragma unroll
            for (int j = kk >> 1; j >= 1; j >>= 1) {
                const u64 oa = __shfl_xor(va, j);
                const bool up      = ((lane & kk) == 0);
                const bool upper   = ((lane & j) != 0);
                const bool takeMax = (upper == up);
                va = (takeMax ? (oa > va) : (oa < va)) ? oa : va;
            }
        }
        const u64 T = __shfl(va, 32);

        // ---- count + exclusive prefix for compaction ----
        int c = 0;
        #pragma unroll
        for (int i = 0; i < 16; ++i) {
            const int m = (i >> 2) * 256 + lane * 4 + (i & 3);
            c += (mkkey(ord[i], m) >= T) ? 1 : 0;
        }
        int s = c;
        #pragma unroll
        for (int off = 1; off < 64; off <<= 1) {
            const int t2 = __shfl_up(s, off);
            if (lane >= off) s += t2;
        }
        const int base = s - c;
        const int Ctot = __shfl(s, 63);

        // ---- compact candidates to LDS (per-wave buffer) ----
        {
            int p = base;
            #pragma unroll
            for (int i = 0; i < 16; ++i) {
                const int m = (i >> 2) * 256 + lane * 4 + (i & 3);
                const u64 k = mkkey(ord[i], m);
                if (k >= T) { if (p < 128) cw[p] = k; ++p; }
            }
        }
        __asm__ volatile("s_waitcnt lgkmcnt(0)" ::: "memory");

        // ---- adaptive bitonic top-32 (exact order) ----
        u64 key;
        if (Ctot <= 64) {
            u64 a0 = (lane < Ctot) ? cw[lane] : 0ULL;
            sort1_desc<1>(&a0, lane);
            key = a0;
        } else if (Ctot <= 128) {
            u64 a[2];
            #pragma unroll
            for (int i = 0; i < 2; ++i) {
                const int ci = lane + 64 * i;
                a[i] = (ci < Ctot) ? cw[ci] : 0ULL;
            }
            sort1_desc<2>(a, lane);
            key = a[0];
        } else {
            key = knn_fallback(ord, lane);
        }

        // ---- epilogue: lane r (<32) holds rank-r neighbor ----
        const int   mS = (int)(~(unsigned)key);
        const float pdv = iord32((unsigned)(key >> 32));
        const int   m0 = __shfl(mS, 0);
        if (lane < KSEL) {
            const size_t obase = ((size_t)(b * NPTS + n)) * KSEL + lane;
            idx_ws[obase]  = mS;
            dist_ws[obase] = -pdv;
            float sv = 0.f;
            #pragma unroll
            for (int d = 0; d < DFEAT; ++d)
                sv = fmaf(xs[d * NPTS + mS], xs[d * NPTS + m0], sv);
            sub_ws[obase] = sv;
        }
    }
}

// ---------------------------------------------------------------------------
// Kernel 2: partial Gram of q = sub^2 over 256-row chunks.
// norm2[b,k,j] = sum_n q[n,k] q[n,j]. grid 128 (b x 4), block 1024.
// ---------------------------------------------------------------------------
__global__ __launch_bounds__(1024) void norm_part_kernel(
        const float* __restrict__ sub_ws, float* __restrict__ npart) {
    __shared__ float qS[256 * 33];
    const int tid = threadIdx.x;
    const int b = blockIdx.x >> 2;
    const int c = blockIdx.x & 3;
    const float* sb = sub_ws + ((size_t)b * NPTS + c * 256) * KSEL;
    for (int i = tid; i < 256 * 32; i += 1024) {
        const float v = sb[i];
        qS[(i >> 5) * 33 + (i & 31)] = v * v;
    }
    __syncthreads();
    const int k = tid >> 5, j = tid & 31;
    float acc = 0.f;
    #pragma unroll 4
    for (int n = 0; n < 256; ++n)
        acc = fmaf(qS[n * 33 + k], qS[n * 33 + j], acc);
    npart[(size_t)blockIdx.x * 1024 + tid] = acc;
}

// ---------------------------------------------------------------------------
// Kernel 3: gm_red + BN1/BN2 f64 partial sums (recip combined inline from
// npart). grid 4096, block 256.
// ---------------------------------------------------------------------------
__global__ __launch_bounds__(256) void gmred_kernel(
        const float* __restrict__ sub_ws, const float* __restrict__ dist_ws,
        const float* __restrict__ npart, const float* __restrict__ w_gm,
        float* __restrict__ gmred_ws, double* __restrict__ part12) {
    __shared__ float recipS[32 * 33];
    __shared__ float subS[8 * 32];
    __shared__ float subWS[8 * 32];
    __shared__ double redS[4][4];

    const int tid = threadIdx.x;
    const int b   = blockIdx.x >> 7;
    const int n0  = (blockIdx.x & 127) * 8;

    for (int i = tid; i < 1024; i += 256) {
        const float sm = npart[((size_t)b * 4 + 0) * 1024 + i]
                       + npart[((size_t)b * 4 + 1) * 1024 + i]
                       + npart[((size_t)b * 4 + 2) * 1024 + i]
                       + npart[((size_t)b * 4 + 3) * 1024 + i];
        recipS[(i >> 5) * 33 + (i & 31)] = 1.0f / fmaxf(sqrtf(sm), 1e-12f);
    }
    {
        const float sv = sub_ws[((size_t)(b * NPTS + n0)) * KSEL + tid];
        subS[tid]  = sv;
        subWS[tid] = sv * w_gm[tid & 31];
    }
    __syncthreads();

    const int r = tid >> 5, k = tid & 31;
    float s = 0.f;
    #pragma unroll
    for (int c = 0; c < 32; ++c)
        s = fmaf(subWS[r * 32 + c], recipS[k * 33 + c], s);
    const float g = subS[r * 32 + k] * s;
    const size_t row = (size_t)(b * NPTS + n0 + r);
    gmred_ws[row * KSEL + k] = g;
    const float dv = dist_ws[row * KSEL + k];

    double s1 = (double)dv, s2 = (double)dv * (double)dv;
    double s3 = (double)g,  s4 = (double)g * (double)g;
    #pragma unroll
    for (int off = 32; off >= 1; off >>= 1) {
        s1 += __shfl_xor(s1, off);
        s2 += __shfl_xor(s2, off);
        s3 += __shfl_xor(s3, off);
        s4 += __shfl_xor(s4, off);
    }
    if ((tid & 63) == 0) {
        const int wv = tid >> 6;
        redS[wv][0] = s1; redS[wv][1] = s2; redS[wv][2] = s3; redS[wv][3] = s4;
    }
    __syncthreads();
    if (tid == 0) {
        double a0 = 0, a1 = 0, a2 = 0, a3 = 0;
        #pragma unroll
        for (int wv = 0; wv < 4; ++wv) {
            a0 += redS[wv][0]; a1 += redS[wv][1]; a2 += redS[wv][2]; a3 += redS[wv][3];
        }
        part12[(size_t)blockIdx.x * 4 + 0] = a0;
        part12[(size_t)blockIdx.x * 4 + 1] = a1;
        part12[(size_t)blockIdx.x * 4 + 2] = a2;
        part12[(size_t)blockIdx.x * 4 + 3] = a3;
    }
}

// ---------------------------------------------------------------------------
// Kernel 4: uc[b,n,o] = sum_d w_up[o,d] * x[b,d,n]. grid 2048, block 256.
// ---------------------------------------------------------------------------
__global__ __launch_bounds__(256) void uc_kernel(
        const float* __restrict__ x, const float* __restrict__ w_up,
        float* __restrict__ uc_ws) {
    __shared__ float wS[NOUT * DFEAT];
    __shared__ float xS[DFEAT * 16];
    const int tid = threadIdx.x;
    const int b  = blockIdx.x >> 6;
    const int n0 = (blockIdx.x & 63) * 16;
    for (int i = tid; i < NOUT * DFEAT; i += 256) wS[i] = w_up[i];
    for (int i = tid; i < DFEAT * 16; i += 256) {
        const int d = i >> 4, c = i & 15;
        xS[i] = x[((size_t)b * DFEAT + d) * NPTS + n0 + c];
    }
    __syncthreads();
    const int o = tid & 63, g = tid >> 6;
    #pragma unroll
    for (int nn = g; nn < 16; nn += 4) {
        float a = 0.f;
        #pragma unroll
        for (int d = 0; d < DFEAT; ++d)
            a = fmaf(wS[o * DFEAT + d], xS[d * 16 + nn], a);
        uc_ws[((size_t)(b * NPTS) + n0 + nn) * NOUT + o] = a;
    }
}

// ---------------------------------------------------------------------------
// Kernel 5: reduce BN1/BN2 partials -> folded scale/offset consts
// ---------------------------------------------------------------------------
__global__ __launch_bounds__(256) void reduce12_kernel(
        const double* __restrict__ part12, int nblocks,
        const float* __restrict__ w_dist,
        const float* __restrict__ g1, const float* __restrict__ b1,
        const float* __restrict__ g2, const float* __restrict__ b2,
        float* __restrict__ consts) {
    __shared__ double S[256][4];
    const int t = threadIdx.x;
    double a0 = 0, a1 = 0, a2 = 0, a3 = 0;
    for (int i = t; i < nblocks; i += 256) {
        a0 += part12[(size_t)i * 4 + 0];
        a1 += part12[(size_t)i * 4 + 1];
        a2 += part12[(size_t)i * 4 + 2];
        a3 += part12[(size_t)i * 4 + 3];
    }
    S[t][0] = a0; S[t][1] = a1; S[t][2] = a2; S[t][3] = a3;
    __syncthreads();
    for (int off = 128; off >= 1; off >>= 1) {
        if (t < off) {
            S[t][0] += S[t + off][0]; S[t][1] += S[t + off][1];
            S[t][2] += S[t + off][2]; S[t][3] += S[t + off][3];
        }
        __syncthreads();
    }
    if (t == 0) {
        const double M = (double)BATCH * NPTS * KSEL;
        const double E1 = S[0][0] / M, E2 = S[0][1] / M;
        const double wd = (double)w_dist[0];
        const double mean1 = wd * E1;
        const double var1  = wd * wd * (E2 - E1 * E1);
        const double istd1 = 1.0 / sqrt(var1 + 1e-5);
        consts[0] = (float)(wd * istd1 * (double)g1[0]);
        consts[1] = (float)((double)b1[0] - mean1 * istd1 * (double)g1[0]);
        const double F1 = S[0][2] / M, F2 = S[0][3] / M;
        const double var2  = F2 - F1 * F1;
        const double istd2 = 1.0 / sqrt(var2 + 1e-5);
        consts[2] = (float)(istd2 * (double)g2[0]);
        consts[3] = (float)((double)b2[0] - F1 * istd2 * (double)g2[0]);
    }
}

// ---------------------------------------------------------------------------
// Kernel 6: gate + BN3 partial stats. grid 512, block 256.
// ---------------------------------------------------------------------------
__global__ __launch_bounds__(256) void gate_stats_kernel(
        const float* __restrict__ dist_ws, const float* __restrict__ gmred_ws,
        const int* __restrict__ idx_ws, const float* __restrict__ uc_ws,
        const float* __restrict__ consts,
        float* __restrict__ gate_ws, double* __restrict__ part3) {
    const int tid = threadIdx.x, lane = tid & 63, w = tid >> 6;
    const int row0 = blockIdx.x * 64;
    const float A1 = consts[0], C1 = consts[1], A2 = consts[2], C2 = consts[3];
    double sum = 0.0, ssq = 0.0;
    for (int rr = 0; rr < 16; ++rr) {
        const int row = row0 + w * 16 + rr;
        const int b = row >> 10;
        float gate = 0.f; int jj = 0;
        if (lane < KSEL) {
            const size_t rbase = (size_t)row * KSEL + lane;
            const float dv = dist_ws[rbase];
            const float gv = gmred_ws[rbase];
            jj = idx_ws[rbase];
            const float z1 = fmaf(dv, A1, C1);
            const float z2 = fmaf(gv, A2, C2);
            const float w1 = 1.f / (1.f + __expf(-z1));
            const float w2 = 1.f / (1.f + __expf(-z2));
            gate = w1 * w2;
            gate_ws[rbase] = gate;
        }
        const float ucr = uc_ws[(size_t)row * NOUT + lane];
        const float* ucb = uc_ws + ((size_t)(b * NPTS)) * NOUT;
        #pragma unroll 8
        for (int k = 0; k < KSEL; ++k) {
            const float gk = __shfl(gate, k);
            const int   jk = __shfl(jj, k);
            const float ucn = ucb[(size_t)jk * NOUT + lane];
            const float up  = fmaf(gk, ucn - ucr, ucr);
            sum += (double)up;
            ssq = fma((double)up, (double)up, ssq);
        }
    }
    __shared__ double p3[4][64][2];
    p3[w][lane][0] = sum; p3[w][lane][1] = ssq;
    __syncthreads();
    if (w == 0) {
        const double s = p3[0][lane][0] + p3[1][lane][0] + p3[2][lane][0] + p3[3][lane][0];
        const double q = p3[0][lane][1] + p3[1][lane][1] + p3[2][lane][1] + p3[3][lane][1];
        part3[((size_t)blockIdx.x * 64 + lane) * 2 + 0] = s;
        part3[((size_t)blockIdx.x * 64 + lane) * 2 + 1] = q;
    }
}

// ---------------------------------------------------------------------------
// Kernel 7: reduce BN3 partials -> per-channel A/C
// ---------------------------------------------------------------------------
__global__ __launch_bounds__(256) void reduce3_kernel(
        const double* __restrict__ part3,
        const float* __restrict__ g3, const float* __restrict__ b3,
        float* __restrict__ consts3) {
    const int t = threadIdx.x;
    const int o = t & 63, gq = t >> 6;
    double s = 0, q = 0;
    for (int i = gq; i < 512; i += 4) {
        s += part3[((size_t)i * 64 + o) * 2 + 0];
        q += part3[((size_t)i * 64 + o) * 2 + 1];
    }
    __shared__ double S[4][64][2];
    S[gq][o][0] = s; S[gq][o][1] = q;
    __syncthreads();
    if (t < 64) {
        const double ss = S[0][o][0] + S[1][o][0] + S[2][o][0] + S[3][o][0];
        const double qq = S[0][o][1] + S[1][o][1] + S[2][o][1] + S[3][o][1];
        const double M = (double)BATCH * NPTS * KSEL;
        const double mean = ss / M;
        const double var  = qq / M - mean * mean;
        const double istd = 1.0 / sqrt(var + 1e-5);
        consts3[o]      = (float)(istd * (double)g3[o]);
        consts3[64 + o] = (float)((double)b3[o] - mean * istd * (double)g3[o]);
    }
}

// ---------------------------------------------------------------------------
// Kernel 8: out[b,o,n] = mean_k lrelu(up*A[o]+C[o])
// ---------------------------------------------------------------------------
__global__ __launch_bounds__(256) void final_kernel(
        const float* __restrict__ gate_ws, const int* __restrict__ idx_ws,
        const float* __restrict__ uc_ws, const float* __restrict__ consts3,
        float* __restrict__ out) {
    const int tid = threadIdx.x, lane = tid & 63, w = tid >> 6;
    const int row0 = blockIdx.x * 64;
    const float A = consts3[lane], C = consts3[64 + lane];
    for (int rr = 0; rr < 16; ++rr) {
        const int row = row0 + w * 16 + rr;
        const int b = row >> 10, n = row & 1023;
        float gate = 0.f; int jj = 0;
        if (lane < KSEL) {
            gate = gate_ws[(size_t)row * KSEL + lane];
            jj   = idx_ws[(size_t)row * KSEL + lane];
        }
        const float ucr = uc_ws[(size_t)row * NOUT + lane];
        const float* ucb = uc_ws + ((size_t)(b * NPTS)) * NOUT;
        float acc = 0.f;
        #pragma unroll 8
        for (int k = 0; k < KSEL; ++k) {
            const float gk = __shfl(gate, k);
            const int   jk = __shfl(jj, k);
            const float ucn = ucb[(size_t)jk * NOUT + lane];
            const float up  = fmaf(gk, ucn - ucr, ucr);
            float z = fmaf(up, A, C);
            z = (z >= 0.f) ? z : 0.02f * z;
            acc += z;
        }
        out[((size_t)b * NOUT + lane) * NPTS + n] = acc * (1.f / 32.f);
    }
}

// ---------------------------------------------------------------------------
extern "C" void kernel_launch(void* const* d_in, const int* in_sizes, int n_in,
                              void* d_out, int out_size, void* d_ws, size_t ws_size,
                              hipStream_t stream) {
    const float* x      = (const float*)d_in[0];
    const float* w_dist = (const float*)d_in[2];
    const float* g1     = (const float*)d_in[3];
    const float* b1     = (const float*)d_in[4];
    const float* w_gm   = (const float*)d_in[5];
    const float* g2     = (const float*)d_in[6];
    const float* b2     = (const float*)d_in[7];
    const float* w_up   = (const float*)d_in[8];
    const float* g3     = (const float*)d_in[9];
    const float* b3     = (const float*)d_in[10];
    float* out = (float*)d_out;

    char* ws = (char*)d_ws;
    int*    idx_ws   = (int*)(ws + 0);
    float*  dist_ws  = (float*)(ws + ((size_t)4 << 20));
    float*  sub_ws   = (float*)(ws + ((size_t)8 << 20));
    float*  gmred_ws = (float*)(ws + ((size_t)12 << 20));
    float*  gate_ws  = (float*)(ws + ((size_t)16 << 20));
    float*  uc_ws    = (float*)(ws + ((size_t)20 << 20));
    double* part12   = (double*)(ws + ((size_t)28 << 20) + 0x20000);
    double* part3    = (double*)(ws + ((size_t)28 << 20) + 0x40000);
    float*  consts   = (float*)(ws + ((size_t)28 << 20) + 0xC0000);
    float*  consts3  = consts + 4;
    // npart lives in the gate region: written by norm_part, consumed by
    // gmred, then overwritten later by gate_stats. 128*1024*4 = 512KB <= 4MB.
    float*  npart    = gate_ws;

    const int knn_lds = (DFEAT * NPTS + NPTS) * 4 + 16 * 128 * 8;  // 104 KB

    knn_kernel<<<dim3(256), dim3(1024), knn_lds, stream>>>(x, idx_ws, dist_ws, sub_ws);
    norm_part_kernel<<<dim3(128), dim3(1024), 0, stream>>>(sub_ws, npart);
    gmred_kernel<<<dim3(4096), dim3(256), 0, stream>>>(sub_ws, dist_ws, npart, w_gm,
                                                       gmred_ws, part12);
    uc_kernel<<<dim3(2048), dim3(256), 0, stream>>>(x, w_up, uc_ws);
    reduce12_kernel<<<dim3(1), dim3(256), 0, stream>>>(part12, 4096, w_dist, g1, b1, g2, b2,
                                                       consts);
    gate_stats_kernel<<<dim3(512), dim3(256), 0, stream>>>(dist_ws, gmred_ws, idx_ws, uc_ws,
                                                           consts, gate_ws, part3);
    reduce3_kernel<<<dim3(1), dim3(256), 0, stream>>>(part3, g3, b3, consts3);
    final_kernel<<<dim3(512), dim3(256), 0, stream>>>(gate_ws, idx_ws, uc_ws, consts3, out);
}

// Round 4
// 248.182 us; speedup vs baseline: 3.2731x; 1.0226x over previous
//
#include <hip/hip_runtime.h>
#include <hip/hip_bf16.h>
#include <math.h>

#define BATCH 32
#define DFEAT 21
#define NPTS 1024
#define KSEL 32
#define NOUT 64

typedef unsigned long long u64;

__device__ __forceinline__ unsigned ord32(float f) {
    unsigned u = __float_as_uint(f);
    return ((int)u >= 0) ? (u | 0x80000000u) : ~u;
}
__device__ __forceinline__ float iord32(unsigned u) {
    unsigned s = (u & 0x80000000u) ? (u & 0x7FFFFFFFu) : ~u;
    return __uint_as_float(s);
}
__device__ __forceinline__ u64 mkkey(unsigned o, int m) {
    return ((u64)o << 32) | (unsigned)(~m);
}

// Dual-stream bitonic sort, descending by u64 key. Element e = lane + 64*i.
// After sort, reg 0 lane r holds rank-r element.
template <int R>
__device__ __forceinline__ void sort2_desc(u64* A, u64* B, int lane) {
    const int NEL = R * 64;
    #pragma unroll
    for (int k = 2; k <= NEL; k <<= 1) {
        #pragma unroll
        for (int j = k >> 1; j >= 1; j >>= 1) {
            if (j >= 64) {
                const int rj = j >> 6;
                #pragma unroll
                for (int i = 0; i < R; ++i) {
                    if ((i & rj) == 0) {
                        const int e = lane + 64 * i;
                        const bool wm = ((e & k) == 0);
                        u64 x = A[i], y = A[i ^ rj];
                        u64 mx = x > y ? x : y, mn = x > y ? y : x;
                        A[i] = wm ? mx : mn; A[i ^ rj] = wm ? mn : mx;
                        x = B[i]; y = B[i ^ rj];
                        mx = x > y ? x : y; mn = x > y ? y : x;
                        B[i] = wm ? mx : mn; B[i ^ rj] = wm ? mn : mx;
                    }
                }
            } else {
                #pragma unroll
                for (int i = 0; i < R; ++i) {
                    const int e = lane + 64 * i;
                    const bool wm = ((e & j) == 0) == ((e & k) == 0);
                    const u64 oa = __shfl_xor(A[i], j);
                    const u64 ob = __shfl_xor(B[i], j);
                    const u64 mxa = A[i] > oa ? A[i] : oa;
                    const u64 mna = A[i] > oa ? oa : A[i];
                    A[i] = wm ? mxa : mna;
                    const u64 mxb = B[i] > ob ? B[i] : ob;
                    const u64 mnb = B[i] > ob ? ob : B[i];
                    B[i] = wm ? mxb : mnb;
                }
            }
        }
    }
}

// Exact rare-path (Ctot > 128, statistically never taken). RECOMPUTES the
// distances from LDS so the hot path does not keep ord[] live across the
// sort. Returns rank-`lane` winner for lane<32.
__device__ __noinline__ u64 knn_fallback(const float* xs, const float* xxs,
                                         int n, int lane) {
    const float4* xs4  = (const float4*)xs;
    const float4* xxs4 = (const float4*)xxs;
    float4 acc[4];
    #pragma unroll
    for (int c = 0; c < 4; ++c) acc[c] = make_float4(0.f, 0.f, 0.f, 0.f);
    for (int d = 0; d < DFEAT; ++d) {
        const float xnd = xs[d * NPTS + n];
        #pragma unroll
        for (int c = 0; c < 4; ++c) {
            const float4 t = xs4[d * 256 + c * 64 + lane];
            acc[c].x = fmaf(t.x, xnd, acc[c].x);
            acc[c].y = fmaf(t.y, xnd, acc[c].y);
            acc[c].z = fmaf(t.z, xnd, acc[c].z);
            acc[c].w = fmaf(t.w, xnd, acc[c].w);
        }
    }
    const float xxn = xxs[n];
    unsigned ord[16];
    #pragma unroll
    for (int c = 0; c < 4; ++c) {
        const float4 xm = xxs4[c * 64 + lane];
        ord[c * 4 + 0] = ord32((2.f * acc[c].x - xxn) - xm.x);
        ord[c * 4 + 1] = ord32((2.f * acc[c].y - xxn) - xm.y);
        ord[c * 4 + 2] = ord32((2.f * acc[c].z - xxn) - xm.z);
        ord[c * 4 + 3] = ord32((2.f * acc[c].w - xxn) - xm.w);
    }
    u64 W = ~0ULL, win = 0ULL;
    for (int it = 0; it < 32; ++it) {
        u64 best = 0ULL;
        #pragma unroll
        for (int i = 0; i < 16; ++i) {
            const int m = (i >> 2) * 256 + lane * 4 + (i & 3);
            const u64 k = mkkey(ord[i], m);
            if (k < W && k > best) best = k;
        }
        #pragma unroll
        for (int off = 32; off >= 1; off >>= 1) {
            const u64 o = __shfl_xor(best, off);
            best = o > best ? o : best;
        }
        win = (lane == it) ? best : win;
        W = best;
    }
    return win;
}

// ---------------------------------------------------------------------------
// Kernel 1: per-row KNN, 2 rows per wave concurrently. float4 m-side LDS
// reads shared across the row pair; threshold prefilter -> compaction ->
// adaptive dual bitonic sort. waves_per_eu(4,4) pins the 128-VGPR budget
// (LDS=120KB forces 1 block/CU = 4 waves/EU regardless).
// grid 256 (32 b x 8 chunks), block 1024 (16 waves x 8 rows).
// ---------------------------------------------------------------------------
__global__ __launch_bounds__(1024)
__attribute__((amdgpu_waves_per_eu(4, 4)))
void knn_kernel(
        const float* __restrict__ x,
        int* __restrict__ idx_ws, float* __restrict__ dist_ws,
        float* __restrict__ sub_ws) {
    extern __shared__ float smem[];
    float* xs  = smem;                       // [21][1024]
    float* xxs = smem + DFEAT * NPTS;        // [1024]
    u64* cand  = (u64*)(smem + DFEAT * NPTS + NPTS);  // [16][2][128]

    const int tid  = threadIdx.x;
    const int lane = tid & 63;
    const int w    = tid >> 6;
    const int b      = blockIdx.x >> 3;
    const int nchunk = blockIdx.x & 7;

    const float* xb = x + (size_t)b * DFEAT * NPTS;
    for (int i = tid; i < DFEAT * NPTS; i += 1024) xs[i] = xb[i];
    __syncthreads();
    {
        const int m = tid;
        float s = 0.f;
        #pragma unroll
        for (int d = 0; d < DFEAT; ++d) { float v = xs[d * NPTS + m]; s = fmaf(v, v, s); }
        xxs[m] = s;
    }
    __syncthreads();

    u64* cwA = cand + (w * 2 + 0) * 128;
    u64* cwB = cand + (w * 2 + 1) * 128;
    const float4* xs4  = (const float4*)xs;
    const float4* xxs4 = (const float4*)xxs;

    const int nbase = nchunk * 128 + w * 8;

    for (int rp = 0; rp < 4; ++rp) {
        const int na = nbase + rp * 2;
        const int nb = na + 1;

        // ---- distances for the pair; m-side float4 reads shared ----
        float4 accA[4], accB[4];
        #pragma unroll
        for (int c = 0; c < 4; ++c) {
            accA[c] = make_float4(0.f, 0.f, 0.f, 0.f);
            accB[c] = make_float4(0.f, 0.f, 0.f, 0.f);
        }
        for (int d = 0; d < DFEAT; ++d) {
            const float* rowp = xs + d * NPTS;
            const float xda = rowp[na];
            const float xdb = rowp[nb];
            #pragma unroll
            for (int c = 0; c < 4; ++c) {
                const float4 t = xs4[d * 256 + c * 64 + lane];
                accA[c].x = fmaf(t.x, xda, accA[c].x);
                accA[c].y = fmaf(t.y, xda, accA[c].y);
                accA[c].z = fmaf(t.z, xda, accA[c].z);
                accA[c].w = fmaf(t.w, xda, accA[c].w);
                accB[c].x = fmaf(t.x, xdb, accB[c].x);
                accB[c].y = fmaf(t.y, xdb, accB[c].y);
                accB[c].z = fmaf(t.z, xdb, accB[c].z);
                accB[c].w = fmaf(t.w, xdb, accB[c].w);
            }
        }
        const float xxna = xxs[na], xxnb = xxs[nb];
        unsigned ordA[16], ordB[16];
        #pragma unroll
        for (int c = 0; c < 4; ++c) {
            const float4 xm = xxs4[c * 64 + lane];
            ordA[c * 4 + 0] = ord32((2.f * accA[c].x - xxna) - xm.x);
            ordA[c * 4 + 1] = ord32((2.f * accA[c].y - xxna) - xm.y);
            ordA[c * 4 + 2] = ord32((2.f * accA[c].z - xxna) - xm.z);
            ordA[c * 4 + 3] = ord32((2.f * accA[c].w - xxna) - xm.w);
            ordB[c * 4 + 0] = ord32((2.f * accB[c].x - xxnb) - xm.x);
            ordB[c * 4 + 1] = ord32((2.f * accB[c].y - xxnb) - xm.y);
            ordB[c * 4 + 2] = ord32((2.f * accB[c].z - xxnb) - xm.z);
            ordB[c * 4 + 3] = ord32((2.f * accB[c].w - xxnb) - xm.w);
        }

        // ---- per-lane max key (u64 compare: tie -> smallest m) ----
        u64 va = mkkey(ordA[0], lane * 4);
        u64 vb = mkkey(ordB[0], lane * 4);
        #pragma unroll
        for (int i = 1; i < 16; ++i) {
            const int m = (i >> 2) * 256 + lane * 4 + (i & 3);
            const u64 ka = mkkey(ordA[i], m);
            const u64 kb = mkkey(ordB[i], m);
            va = ka > va ? ka : va;
            vb = kb > vb ? kb : vb;
        }

        // ---- threshold = 32nd largest of 64 lane maxima (asc bitonic) ----
        #pragma unroll
        for (int kk = 2; kk <= 64; kk <<= 1) {
            #pragma unroll
            for (int j = kk >> 1; j >= 1; j >>= 1) {
                const u64 oa = __shfl_xor(va, j);
                const u64 ob = __shfl_xor(vb, j);
                const bool up      = ((lane & kk) == 0);
                const bool upper   = ((lane & j) != 0);
                const bool takeMax = (upper == up);
                va = (takeMax ? (oa > va) : (oa < va)) ? oa : va;
                vb = (takeMax ? (ob > vb) : (ob < vb)) ? ob : vb;
            }
        }
        const u64 Ta = __shfl(va, 32);
        const u64 Tb = __shfl(vb, 32);

        // ---- count + exclusive prefix for compaction ----
        int ca = 0, cb = 0;
        #pragma unroll
        for (int i = 0; i < 16; ++i) {
            const int m = (i >> 2) * 256 + lane * 4 + (i & 3);
            ca += (mkkey(ordA[i], m) >= Ta) ? 1 : 0;
            cb += (mkkey(ordB[i], m) >= Tb) ? 1 : 0;
        }
        int sa = ca, sb = cb;
        #pragma unroll
        for (int off = 1; off < 64; off <<= 1) {
            const int t2a = __shfl_up(sa, off);
            const int t2b = __shfl_up(sb, off);
            if (lane >= off) { sa += t2a; sb += t2b; }
        }
        const int baseA = sa - ca, baseB = sb - cb;
        const int CtA = __shfl(sa, 63), CtB = __shfl(sb, 63);

        // ---- compact candidates to LDS; ordA/ordB die here ----
        {
            int p = baseA;
            #pragma unroll
            for (int i = 0; i < 16; ++i) {
                const int m = (i >> 2) * 256 + lane * 4 + (i & 3);
                const u64 k = mkkey(ordA[i], m);
                if (k >= Ta) { if (p < 128) cwA[p] = k; ++p; }
            }
            p = baseB;
            #pragma unroll
            for (int i = 0; i < 16; ++i) {
                const int m = (i >> 2) * 256 + lane * 4 + (i & 3);
                const u64 k = mkkey(ordB[i], m);
                if (k >= Tb) { if (p < 128) cwB[p] = k; ++p; }
            }
        }
        __asm__ volatile("s_waitcnt lgkmcnt(0)" ::: "memory");

        // ---- adaptive dual bitonic top-32 (exact order) ----
        u64 keyA, keyB;
        if (CtA <= 128 && CtB <= 128) {
            if (CtA <= 64 && CtB <= 64) {
                u64 a0 = (lane < CtA) ? cwA[lane] : 0ULL;
                u64 b0 = (lane < CtB) ? cwB[lane] : 0ULL;
                sort2_desc<1>(&a0, &b0, lane);
                keyA = a0; keyB = b0;
            } else {
                u64 a[2], bb[2];
                #pragma unroll
                for (int i = 0; i < 2; ++i) {
                    const int ci = lane + 64 * i;
                    a[i]  = (ci < CtA) ? cwA[ci] : 0ULL;
                    bb[i] = (ci < CtB) ? cwB[ci] : 0ULL;
                }
                sort2_desc<2>(a, bb, lane);
                keyA = a[0]; keyB = bb[0];
            }
        } else {
            keyA = knn_fallback(xs, xxs, na, lane);
            keyB = knn_fallback(xs, xxs, nb, lane);
        }

        // ---- epilogue: lane r (<32) holds rank-r neighbor ----
        const int   mA = (int)(~(unsigned)keyA);
        const int   mB = (int)(~(unsigned)keyB);
        const float pdA = iord32((unsigned)(keyA >> 32));
        const float pdB = iord32((unsigned)(keyB >> 32));
        const int m0A = __shfl(mA, 0);
        const int m0B = __shfl(mB, 0);
        if (lane < KSEL) {
            const size_t oA = ((size_t)(b * NPTS + na)) * KSEL + lane;
            const size_t oB = ((size_t)(b * NPTS + nb)) * KSEL + lane;
            idx_ws[oA]  = mA;          idx_ws[oB]  = mB;
            dist_ws[oA] = -pdA;        dist_ws[oB] = -pdB;
            float svA = 0.f, svB = 0.f;
            #pragma unroll
            for (int d = 0; d < DFEAT; ++d) {
                svA = fmaf(xs[d * NPTS + mA], xs[d * NPTS + m0A], svA);
                svB = fmaf(xs[d * NPTS + mB], xs[d * NPTS + m0B], svB);
            }
            sub_ws[oA] = svA;          sub_ws[oB] = svB;
        }
    }
}

// ---------------------------------------------------------------------------
// Kernel 2: partial Gram of q = sub^2 over 256-row chunks.
// norm2[b,k,j] = sum_n q[n,k] q[n,j]. grid 128 (b x 4), block 1024.
// ---------------------------------------------------------------------------
__global__ __launch_bounds__(1024) void norm_part_kernel(
        const float* __restrict__ sub_ws, float* __restrict__ npart) {
    __shared__ float qS[256 * 33];
    const int tid = threadIdx.x;
    const int b = blockIdx.x >> 2;
    const int c = blockIdx.x & 3;
    const float* sb = sub_ws + ((size_t)b * NPTS + c * 256) * KSEL;
    for (int i = tid; i < 256 * 32; i += 1024) {
        const float v = sb[i];
        qS[(i >> 5) * 33 + (i & 31)] = v * v;
    }
    __syncthreads();
    const int k = tid >> 5, j = tid & 31;
    float acc = 0.f;
    #pragma unroll 4
    for (int n = 0; n < 256; ++n)
        acc = fmaf(qS[n * 33 + k], qS[n * 33 + j], acc);
    npart[(size_t)blockIdx.x * 1024 + tid] = acc;
}

// ---------------------------------------------------------------------------
// Kernel 3: gm_red + BN1/BN2 f64 partial sums (recip combined inline from
// npart). grid 4096, block 256.
// ---------------------------------------------------------------------------
__global__ __launch_bounds__(256) void gmred_kernel(
        const float* __restrict__ sub_ws, const float* __restrict__ dist_ws,
        const float* __restrict__ npart, const float* __restrict__ w_gm,
        float* __restrict__ gmred_ws, double* __restrict__ part12) {
    __shared__ float recipS[32 * 33];
    __shared__ float subS[8 * 32];
    __shared__ float subWS[8 * 32];
    __shared__ double redS[4][4];

    const int tid = threadIdx.x;
    const int b   = blockIdx.x >> 7;
    const int n0  = (blockIdx.x & 127) * 8;

    for (int i = tid; i < 1024; i += 256) {
        const float sm = npart[((size_t)b * 4 + 0) * 1024 + i]
                       + npart[((size_t)b * 4 + 1) * 1024 + i]
                       + npart[((size_t)b * 4 + 2) * 1024 + i]
                       + npart[((size_t)b * 4 + 3) * 1024 + i];
        recipS[(i >> 5) * 33 + (i & 31)] = 1.0f / fmaxf(sqrtf(sm), 1e-12f);
    }
    {
        const float sv = sub_ws[((size_t)(b * NPTS + n0)) * KSEL + tid];
        subS[tid]  = sv;
        subWS[tid] = sv * w_gm[tid & 31];
    }
    __syncthreads();

    const int r = tid >> 5, k = tid & 31;
    float s = 0.f;
    #pragma unroll
    for (int c = 0; c < 32; ++c)
        s = fmaf(subWS[r * 32 + c], recipS[k * 33 + c], s);
    const float g = subS[r * 32 + k] * s;
    const size_t row = (size_t)(b * NPTS + n0 + r);
    gmred_ws[row * KSEL + k] = g;
    const float dv = dist_ws[row * KSEL + k];

    double s1 = (double)dv, s2 = (double)dv * (double)dv;
    double s3 = (double)g,  s4 = (double)g * (double)g;
    #pragma unroll
    for (int off = 32; off >= 1; off >>= 1) {
        s1 += __shfl_xor(s1, off);
        s2 += __shfl_xor(s2, off);
        s3 += __shfl_xor(s3, off);
        s4 += __shfl_xor(s4, off);
    }
    if ((tid & 63) == 0) {
        const int wv = tid >> 6;
        redS[wv][0] = s1; redS[wv][1] = s2; redS[wv][2] = s3; redS[wv][3] = s4;
    }
    __syncthreads();
    if (tid == 0) {
        double a0 = 0, a1 = 0, a2 = 0, a3 = 0;
        #pragma unroll
        for (int wv = 0; wv < 4; ++wv) {
            a0 += redS[wv][0]; a1 += redS[wv][1]; a2 += redS[wv][2]; a3 += redS[wv][3];
        }
        part12[(size_t)blockIdx.x * 4 + 0] = a0;
        part12[(size_t)blockIdx.x * 4 + 1] = a1;
        part12[(size_t)blockIdx.x * 4 + 2] = a2;
        part12[(size_t)blockIdx.x * 4 + 3] = a3;
    }
}

// ---------------------------------------------------------------------------
// Kernel 4: uc[b,n,o] = sum_d w_up[o,d] * x[b,d,n]. grid 2048, block 256.
// ---------------------------------------------------------------------------
__global__ __launch_bounds__(256) void uc_kernel(
        const float* __restrict__ x, const float* __restrict__ w_up,
        float* __restrict__ uc_ws) {
    __shared__ float wS[NOUT * DFEAT];
    __shared__ float xS[DFEAT * 16];
    const int tid = threadIdx.x;
    const int b  = blockIdx.x >> 6;
    const int n0 = (blockIdx.x & 63) * 16;
    for (int i = tid; i < NOUT * DFEAT; i += 256) wS[i] = w_up[i];
    for (int i = tid; i < DFEAT * 16; i += 256) {
        const int d = i >> 4, c = i & 15;
        xS[i] = x[((size_t)b * DFEAT + d) * NPTS + n0 + c];
    }
    __syncthreads();
    const int o = tid & 63, g = tid >> 6;
    #pragma unroll
    for (int nn = g; nn < 16; nn += 4) {
        float a = 0.f;
        #pragma unroll
        for (int d = 0; d < DFEAT; ++d)
            a = fmaf(wS[o * DFEAT + d], xS[d * 16 + nn], a);
        uc_ws[((size_t)(b * NPTS) + n0 + nn) * NOUT + o] = a;
    }
}

// ---------------------------------------------------------------------------
// Kernel 5: reduce BN1/BN2 partials -> folded scale/offset consts
// ---------------------------------------------------------------------------
__global__ __launch_bounds__(256) void reduce12_kernel(
        const double* __restrict__ part12, int nblocks,
        const float* __restrict__ w_dist,
        const float* __restrict__ g1, const float* __restrict__ b1,
        const float* __restrict__ g2, const float* __restrict__ b2,
        float* __restrict__ consts) {
    __shared__ double S[256][4];
    const int t = threadIdx.x;
    double a0 = 0, a1 = 0, a2 = 0, a3 = 0;
    for (int i = t; i < nblocks; i += 256) {
        a0 += part12[(size_t)i * 4 + 0];
        a1 += part12[(size_t)i * 4 + 1];
        a2 += part12[(size_t)i * 4 + 2];
        a3 += part12[(size_t)i * 4 + 3];
    }
    S[t][0] = a0; S[t][1] = a1; S[t][2] = a2; S[t][3] = a3;
    __syncthreads();
    for (int off = 128; off >= 1; off >>= 1) {
        if (t < off) {
            S[t][0] += S[t + off][0]; S[t][1] += S[t + off][1];
            S[t][2] += S[t + off][2]; S[t][3] += S[t + off][3];
        }
        __syncthreads();
    }
    if (t == 0) {
        const double M = (double)BATCH * NPTS * KSEL;
        const double E1 = S[0][0] / M, E2 = S[0][1] / M;
        const double wd = (double)w_dist[0];
        const double mean1 = wd * E1;
        const double var1  = wd * wd * (E2 - E1 * E1);
        const double istd1 = 1.0 / sqrt(var1 + 1e-5);
        consts[0] = (float)(wd * istd1 * (double)g1[0]);
        consts[1] = (float)((double)b1[0] - mean1 * istd1 * (double)g1[0]);
        const double F1 = S[0][2] / M, F2 = S[0][3] / M;
        const double var2  = F2 - F1 * F1;
        const double istd2 = 1.0 / sqrt(var2 + 1e-5);
        consts[2] = (float)(istd2 * (double)g2[0]);
        consts[3] = (float)((double)b2[0] - F1 * istd2 * (double)g2[0]);
    }
}

// ---------------------------------------------------------------------------
// Kernel 6: gate + BN3 partial stats. grid 512, block 256.
// ---------------------------------------------------------------------------
__global__ __launch_bounds__(256) void gate_stats_kernel(
        const float* __restrict__ dist_ws, const float* __restrict__ gmred_ws,
        const int* __restrict__ idx_ws, const float* __restrict__ uc_ws,
        const float* __restrict__ consts,
        float* __restrict__ gate_ws, double* __restrict__ part3) {
    const int tid = threadIdx.x, lane = tid & 63, w = tid >> 6;
    const int row0 = blockIdx.x * 64;
    const float A1 = consts[0], C1 = consts[1], A2 = consts[2], C2 = consts[3];
    double sum = 0.0, ssq = 0.0;
    for (int rr = 0; rr < 16; ++rr) {
        const int row = row0 + w * 16 + rr;
        const int b = row >> 10;
        float gate = 0.f; int jj = 0;
        if (lane < KSEL) {
            const size_t rbase = (size_t)row * KSEL + lane;
            const float dv = dist_ws[rbase];
            const float gv = gmred_ws[rbase];
            jj = idx_ws[rbase];
            const float z1 = fmaf(dv, A1, C1);
            const float z2 = fmaf(gv, A2, C2);
            const float w1 = 1.f / (1.f + __expf(-z1));
            const float w2 = 1.f / (1.f + __expf(-z2));
            gate = w1 * w2;
            gate_ws[rbase] = gate;
        }
        const float ucr = uc_ws[(size_t)row * NOUT + lane];
        const float* ucb = uc_ws + ((size_t)(b * NPTS)) * NOUT;
        #pragma unroll 8
        for (int k = 0; k < KSEL; ++k) {
            const float gk = __shfl(gate, k);
            const int   jk = __shfl(jj, k);
            const float ucn = ucb[(size_t)jk * NOUT + lane];
            const float up  = fmaf(gk, ucn - ucr, ucr);
            sum += (double)up;
            ssq = fma((double)up, (double)up, ssq);
        }
    }
    __shared__ double p3[4][64][2];
    p3[w][lane][0] = sum; p3[w][lane][1] = ssq;
    __syncthreads();
    if (w == 0) {
        const double s = p3[0][lane][0] + p3[1][lane][0] + p3[2][lane][0] + p3[3][lane][0];
        const double q = p3[0][lane][1] + p3[1][lane][1] + p3[2][lane][1] + p3[3][lane][1];
        part3[((size_t)blockIdx.x * 64 + lane) * 2 + 0] = s;
        part3[((size_t)blockIdx.x * 64 + lane) * 2 + 1] = q;
    }
}

// ---------------------------------------------------------------------------
// Kernel 7: reduce BN3 partials -> per-channel A/C
// ---------------------------------------------------------------------------
__global__ __launch_bounds__(256) void reduce3_kernel(
        const double* __restrict__ part3,
        const float* __restrict__ g3, const float* __restrict__ b3,
        float* __restrict__ consts3) {
    const int t = threadIdx.x;
    const int o = t & 63, gq = t >> 6;
    double s = 0, q = 0;
    for (int i = gq; i < 512; i += 4) {
        s += part3[((size_t)i * 64 + o) * 2 + 0];
        q += part3[((size_t)i * 64 + o) * 2 + 1];
    }
    __shared__ double S[4][64][2];
    S[gq][o][0] = s; S[gq][o][1] = q;
    __syncthreads();
    if (t < 64) {
        const double ss = S[0][o][0] + S[1][o][0] + S[2][o][0] + S[3][o][0];
        const double qq = S[0][o][1] + S[1][o][1] + S[2][o][1] + S[3][o][1];
        const double M = (double)BATCH * NPTS * KSEL;
        const double mean = ss / M;
        const double var  = qq / M - mean * mean;
        const double istd = 1.0 / sqrt(var + 1e-5);
        consts3[o]      = (float)(istd * (double)g3[o]);
        consts3[64 + o] = (float)((double)b3[o] - mean * istd * (double)g3[o]);
    }
}

// ---------------------------------------------------------------------------
// Kernel 8: out[b,o,n] = mean_k lrelu(up*A[o]+C[o])
// ---------------------------------------------------------------------------
__global__ __launch_bounds__(256) void final_kernel(
        const float* __restrict__ gate_ws, const int* __restrict__ idx_ws,
        const float* __restrict__ uc_ws, const float* __restrict__ consts3,
        float* __restrict__ out) {
    const int tid = threadIdx.x, lane = tid & 63, w = tid >> 6;
    const int row0 = blockIdx.x * 64;
    const float A = consts3[lane], C = consts3[64 + lane];
    for (int rr = 0; rr < 16; ++rr) {
        const int row = row0 + w * 16 + rr;
        const int b = row >> 10, n = row & 1023;
        float gate = 0.f; int jj = 0;
        if (lane < KSEL) {
            gate = gate_ws[(size_t)row * KSEL + lane];
            jj   = idx_ws[(size_t)row * KSEL + lane];
        }
        const float ucr = uc_ws[(size_t)row * NOUT + lane];
        const float* ucb = uc_ws + ((size_t)(b * NPTS)) * NOUT;
        float acc = 0.f;
        #pragma unroll 8
        for (int k = 0; k < KSEL; ++k) {
            const float gk = __shfl(gate, k);
            const int   jk = __shfl(jj, k);
            const float ucn = ucb[(size_t)jk * NOUT + lane];
            const float up  = fmaf(gk, ucn - ucr, ucr);
            float z = fmaf(up, A, C);
            z = (z >= 0.f) ? z : 0.02f * z;
            acc += z;
        }
        out[((size_t)b * NOUT + lane) * NPTS + n] = acc * (1.f / 32.f);
    }
}

// ---------------------------------------------------------------------------
extern "C" void kernel_launch(void* const* d_in, const int* in_sizes, int n_in,
                              void* d_out, int out_size, void* d_ws, size_t ws_size,
                              hipStream_t stream) {
    const float* x      = (const float*)d_in[0];
    const float* w_dist = (const float*)d_in[2];
    const float* g1     = (const float*)d_in[3];
    const float* b1     = (const float*)d_in[4];
    const float* w_gm   = (const float*)d_in[5];
    const float* g2     = (const float*)d_in[6];
    const float* b2     = (const float*)d_in[7];
    const float* w_up   = (const float*)d_in[8];
    const float* g3     = (const float*)d_in[9];
    const float* b3     = (const float*)d_in[10];
    float* out = (float*)d_out;

    char* ws = (char*)d_ws;
    int*    idx_ws   = (int*)(ws + 0);
    float*  dist_ws  = (float*)(ws + ((size_t)4 << 20));
    float*  sub_ws   = (float*)(ws + ((size_t)8 << 20));
    float*  gmred_ws = (float*)(ws + ((size_t)12 << 20));
    float*  gate_ws  = (float*)(ws + ((size_t)16 << 20));
    float*  uc_ws    = (float*)(ws + ((size_t)20 << 20));
    double* part12   = (double*)(ws + ((size_t)28 << 20) + 0x20000);
    double* part3    = (double*)(ws + ((size_t)28 << 20) + 0x40000);
    float*  consts   = (float*)(ws + ((size_t)28 << 20) + 0xC0000);
    float*  consts3  = consts + 4;
    // npart lives in the gate region: written by norm_part, consumed by
    // gmred, then overwritten later by gate_stats. 128*1024*4 = 512KB <= 4MB.
    float*  npart    = gate_ws;

    const int knn_lds = (DFEAT * NPTS + NPTS) * 4 + 16 * 2 * 128 * 8;  // 120 KB

    knn_kernel<<<dim3(256), dim3(1024), knn_lds, stream>>>(x, idx_ws, dist_ws, sub_ws);
    norm_part_kernel<<<dim3(128), dim3(1024), 0, stream>>>(sub_ws, npart);
    gmred_kernel<<<dim3(4096), dim3(256), 0, stream>>>(sub_ws, dist_ws, npart, w_gm,
                                                       gmred_ws, part12);
    uc_kernel<<<dim3(2048), dim3(256), 0, stream>>>(x, w_up, uc_ws);
    reduce12_kernel<<<dim3(1), dim3(256), 0, stream>>>(part12, 4096, w_dist, g1, b1, g2, b2,
                                                       consts);
    gate_stats_kernel<<<dim3(512), dim3(256), 0, stream>>>(dist_ws, gmred_ws, idx_ws, uc_ws,
                                                           consts, gate_ws, part3);
    reduce3_kernel<<<dim3(1), dim3(256), 0, stream>>>(part3, g3, b3, consts3);
    final_kernel<<<dim3(512), dim3(256), 0, stream>>>(gate_ws, idx_ws, uc_ws, consts3, out);
}